// Round 3
// baseline (878.885 us; speedup 1.0000x reference)
//
#include <hip/hip_runtime.h>

using f16 = _Float16;
typedef f16 f16x8 __attribute__((ext_vector_type(8)));
typedef f16 f16x4 __attribute__((ext_vector_type(4)));
typedef float f32x4 __attribute__((ext_vector_type(4)));

#define TOKENS 4096   // B*N
#define KD 2048       // 2*DIM  (GEMM inner dim, k = 2*dk + ck)
#define NQ 6144       // qkv cols: which*2048 + h*128 + d*2 + c
#define QKW 4096      // width of the Q,K buffer (V split off to Vt)

__device__ __forceinline__ void gload_lds16(const void* g, void* l) {
  __builtin_amdgcn_global_load_lds(
      (__attribute__((address_space(1))) void*)(unsigned long long)g,
      (__attribute__((address_space(3))) void*)l, 16, 0, 0);
}

// ---------------- prep kernels ----------------
__global__ __launch_bounds__(256) void cast_x_kernel(const float* __restrict__ x,
                                                     f16* __restrict__ X, int n) {
  int i = blockIdx.x * 256 + threadIdx.x;
  if (i < n) X[i] = (f16)x[i];
}

__global__ __launch_bounds__(256) void pack_wqkv_kernel(const float* __restrict__ wr,
    const float* __restrict__ wi, const float* __restrict__ br, const float* __restrict__ bi,
    f16* __restrict__ Wp, float* __restrict__ biasq) {
  int idx = blockIdx.x * 256 + threadIdx.x;
  if (idx >= NQ * KD) return;
  int j = idx >> 11;
  int k = idx & 2047;
  int which = j >> 11;
  int rem = j & 2047;
  int h = rem >> 7, t = rem & 127, d = t >> 1, c = t & 1;
  int o = which * 1024 + h * 64 + d;
  int dk = k >> 1, ck = k & 1;
  float wrv = wr[o * 1024 + dk], wiv = wi[o * 1024 + dk];
  float v = (c == 0) ? ((ck == 0) ? wrv : -wiv) : ((ck == 0) ? wiv : wrv);
  Wp[idx] = (f16)v;
  if (k == 0) biasq[j] = (c == 0) ? (br[o] - bi[o]) : (br[o] + bi[o]);
}

__global__ __launch_bounds__(256) void pack_wo_kernel(const float* __restrict__ wr,
    const float* __restrict__ wi, const float* __restrict__ br, const float* __restrict__ bi,
    f16* __restrict__ Wp, float* __restrict__ biaso) {
  int idx = blockIdx.x * 256 + threadIdx.x;
  if (idx >= KD * KD) return;
  int j = idx >> 11, k = idx & 2047;
  int jo = j >> 1, c = j & 1;
  int dk = k >> 1, ck = k & 1;
  float wrv = wr[jo * 1024 + dk], wiv = wi[jo * 1024 + dk];
  float v = (c == 0) ? ((ck == 0) ? wrv : -wiv) : ((ck == 0) ? wiv : wrv);
  Wp[idx] = (f16)v;
  if (k == 0) biaso[j] = (c == 0) ? (br[jo] - bi[jo]) : (br[jo] + bi[jo]);
}

// ---------------- GEMM: C[m][n] = sum_k A[m][k]*B[n][k] + bias[n] ----------------
// 128x128 tile, BK=32, 4 waves (2x2). Cols >= 4096 (V of qkv) are written
// TRANSPOSED to vt[b*16+h][d][token] so attention's PV can vector-load V columns.
template<bool HALF_OUT>
__global__ __launch_bounds__(256) void gemm_tn(const f16* __restrict__ A,
    const f16* __restrict__ B, const float* __restrict__ bias,
    void* __restrict__ Cout, int ldc, f16* __restrict__ vt) {
  __shared__ f16 ldsA[128 * 32];
  __shared__ f16 ldsB[128 * 32];
  const int tid = threadIdx.x;
  const int wave = tid >> 6, lane = tid & 63;
  const int lo = lane & 15, hi = lane >> 4;
  const int m0 = blockIdx.y * 128, n0 = blockIdx.x * 128;
  const int wm = wave >> 1, wn = wave & 1;

  const int srow = wave * 32 + (lane >> 2);
  const int scol = (lane & 3) * 8;
  const f16* gA0 = A + (size_t)(m0 + srow) * KD + scol;
  const f16* gA1 = gA0 + (size_t)16 * KD;
  const f16* gB0 = B + (size_t)(n0 + srow) * KD + scol;
  const f16* gB1 = gB0 + (size_t)16 * KD;
  f16* lA0 = &ldsA[wave * 1024];
  f16* lA1 = &ldsA[wave * 1024 + 512];
  f16* lB0 = &ldsB[wave * 1024];
  f16* lB1 = &ldsB[wave * 1024 + 512];

  f32x4 acc[4][4] = {};

  for (int kt = 0; kt < KD; kt += 32) {
    gload_lds16(gA0, lA0);
    gload_lds16(gA1, lA1);
    gload_lds16(gB0, lB0);
    gload_lds16(gB1, lB1);
    gA0 += 32; gA1 += 32; gB0 += 32; gB1 += 32;
    __syncthreads();
    f16x8 af[4], bf[4];
    #pragma unroll
    for (int mi = 0; mi < 4; ++mi)
      af[mi] = *(const f16x8*)&ldsA[(wm * 64 + mi * 16 + lo) * 32 + hi * 8];
    #pragma unroll
    for (int ni = 0; ni < 4; ++ni)
      bf[ni] = *(const f16x8*)&ldsB[(wn * 64 + ni * 16 + lo) * 32 + hi * 8];
    #pragma unroll
    for (int mi = 0; mi < 4; ++mi)
      #pragma unroll
      for (int ni = 0; ni < 4; ++ni)
        acc[mi][ni] = __builtin_amdgcn_mfma_f32_16x16x32_f16(af[mi], bf[ni], acc[mi][ni], 0, 0, 0);
    __syncthreads();
  }

  #pragma unroll
  for (int mi = 0; mi < 4; ++mi) {
    #pragma unroll
    for (int ni = 0; ni < 4; ++ni) {
      const int colbase = n0 + wn * 64 + ni * 16;
      const int col = colbase + lo;
      const float bv = bias[col];
      const int rowb = m0 + wm * 64 + mi * 16 + hi * 4;  // D: row = 4*hi + r, col = lo
      if (vt != nullptr && colbase >= 4096) {
        // V block -> transposed store: 4 consecutive tokens at fixed d
        const int dcol = col - 4096;
        const int hh = dcol >> 7, dd = dcol & 127;
        const int bb = rowb >> 11, tok = rowb & 2047;
        f16x4 pk;
        #pragma unroll
        for (int r = 0; r < 4; ++r) pk[r] = (f16)(acc[mi][ni][r] + bv);
        *(f16x4*)(vt + (((size_t)(bb * 16 + hh) * 128 + dd) * 2048 + tok)) = pk;
      } else {
        #pragma unroll
        for (int r = 0; r < 4; ++r) {
          const float v = acc[mi][ni][r] + bv;
          if (HALF_OUT) ((f16*)Cout)[(size_t)(rowb + r) * ldc + col] = (f16)v;
          else          ((float*)Cout)[(size_t)(rowb + r) * ldc + col] = v;
        }
      }
    }
  }
}

// ---------------- flash attention, per (b,h), wave = 16 q-rows, KV tile 32 ----
// Swapped QK^T: mfma(K,Q) => lane holds S[q=lo][kv = t + 16*tt + 4*hi + r].
// P is directly the A-fragment of mfma_f32_16x16x16f16 for PV; V read from Vt
// (d-major) as contiguous f16x4 over tokens.
__global__ __launch_bounds__(256) void attn_kernel(const f16* __restrict__ qk,
                                                   const f16* __restrict__ vt,
                                                   f16* __restrict__ outp) {
  const int wave = threadIdx.x >> 6, lane = threadIdx.x & 63;
  const int lo = lane & 15, hi = lane >> 4;
  const int b = blockIdx.y >> 4, h = blockIdx.y & 15;
  const int q0 = blockIdx.x * 64 + wave * 16;

  const f16* Qb = qk + (size_t)b * 2048 * QKW + h * 128;
  const f16* Kb = Qb + 2048;
  const f16* Vtb = vt + (size_t)(b * 16 + h) * 128 * 2048;

  f16x8 qf[4];
  #pragma unroll
  for (int c = 0; c < 4; ++c) {
    qf[c] = *(const f16x8*)(Qb + (size_t)(q0 + lo) * QKW + c * 32 + hi * 8);
    qf[c] *= (f16)0.125f;   // fold attn scale (exact pow2) into Q
  }

  f32x4 o[8];
  #pragma unroll
  for (int dc = 0; dc < 8; ++dc) o[dc] = (f32x4){0.f, 0.f, 0.f, 0.f};
  float m_run = -INFINITY, l_run = 0.f;

  for (int t = 0; t < 2048; t += 32) {
    f32x4 s0 = {0.f, 0.f, 0.f, 0.f}, s1 = {0.f, 0.f, 0.f, 0.f};
    #pragma unroll
    for (int c = 0; c < 4; ++c) {
      f16x8 kf = *(const f16x8*)(Kb + (size_t)(t + lo) * QKW + c * 32 + hi * 8);
      s0 = __builtin_amdgcn_mfma_f32_16x16x32_f16(kf, qf[c], s0, 0, 0, 0);
    }
    #pragma unroll
    for (int c = 0; c < 4; ++c) {
      f16x8 kf = *(const f16x8*)(Kb + (size_t)(t + 16 + lo) * QKW + c * 32 + hi * 8);
      s1 = __builtin_amdgcn_mfma_f32_16x16x32_f16(kf, qf[c], s1, 0, 0, 0);
    }

    // per-q max over this 32-kv tile (q = lo; kv spread over regs + hi groups)
    float pm = fmaxf(fmaxf(fmaxf(s0[0], s0[1]), fmaxf(s0[2], s0[3])),
                     fmaxf(fmaxf(s1[0], s1[1]), fmaxf(s1[2], s1[3])));
    pm = fmaxf(pm, __shfl_xor(pm, 16));
    pm = fmaxf(pm, __shfl_xor(pm, 32));

    // defer-max (T13): only rescale when some row's max grew by > 8
    if (!__all(pm - m_run <= 8.f)) {
      const float corr = __expf(m_run - pm);   // exp(-inf)=0 on first tile
      m_run = pm;
      float co[4];
      #pragma unroll
      for (int r = 0; r < 4; ++r) co[r] = __shfl(corr, hi * 4 + r);
      #pragma unroll
      for (int dc = 0; dc < 8; ++dc)
        #pragma unroll
        for (int r = 0; r < 4; ++r) o[dc][r] *= co[r];
      l_run *= corr;
    }

    float psum = 0.f;
    f16x4 pf0, pf1;
    #pragma unroll
    for (int r = 0; r < 4; ++r) {
      float p0 = __expf(s0[r] - m_run);
      float p1 = __expf(s1[r] - m_run);
      psum += p0 + p1;
      pf0[r] = (f16)p0;
      pf1[r] = (f16)p1;
    }
    psum += __shfl_xor(psum, 16);
    psum += __shfl_xor(psum, 32);
    l_run += psum;

    #pragma unroll
    for (int dc = 0; dc < 8; ++dc) {
      const f16* vp = Vtb + (size_t)(dc * 16 + lo) * 2048 + t + hi * 4;
      f16x4 vf0 = *(const f16x4*)vp;
      f16x4 vf1 = *(const f16x4*)(vp + 16);
      o[dc] = __builtin_amdgcn_mfma_f32_16x16x16f16(pf0, vf0, o[dc], 0, 0, 0);
      o[dc] = __builtin_amdgcn_mfma_f32_16x16x16f16(pf1, vf1, o[dc], 0, 0, 0);
    }
  }

  float inv[4];
  #pragma unroll
  for (int r = 0; r < 4; ++r) inv[r] = 1.f / __shfl(l_run, hi * 4 + r);

  const int tok0 = b * 2048 + q0;
  #pragma unroll
  for (int dc = 0; dc < 8; ++dc)
    #pragma unroll
    for (int r = 0; r < 4; ++r)
      outp[(size_t)(tok0 + hi * 4 + r) * KD + h * 128 + dc * 16 + lo] =
          (f16)(o[dc][r] * inv[r]);
}

// ---------------- launch ----------------
extern "C" void kernel_launch(void* const* d_in, const int* in_sizes, int n_in,
                              void* d_out, int out_size, void* d_ws, size_t ws_size,
                              hipStream_t stream) {
  const float* x      = (const float*)d_in[0];
  const float* wqkv_r = (const float*)d_in[1];
  const float* wqkv_i = (const float*)d_in[2];
  const float* bqkv_r = (const float*)d_in[3];
  const float* bqkv_i = (const float*)d_in[4];
  const float* wo_r   = (const float*)d_in[5];
  const float* wo_i   = (const float*)d_in[6];
  const float* bo_r   = (const float*)d_in[7];
  const float* bo_i   = (const float*)d_in[8];
  float* out = (float*)d_out;
  char* ws = (char*)d_ws;

  // workspace layout (~100.7 MB, same footprint as round 2)
  f16*   Wqkv_p = (f16*)(ws + 0);              // 6144*2048*2   = 25165824
  f16*   Wo_p   = (f16*)(ws + 25165824);       // 2048*2048*2   =  8388608
  float* biasq  = (float*)(ws + 33554432);     // 6144*4
  float* biaso  = (float*)(ws + 33579008);     // 2048*4
  f16*   qkQK   = (f16*)(ws + 33587200);       // 4096*4096*2   = 33554432 (Q,K)
  f16*   Vt     = (f16*)(ws + 67141632);       // 32*128*2048*2 = 16777216 (V^T)
  f16*   Xh     = (f16*)(ws + 83918848);       // 4096*2048*2   = 16777216
  f16*   attn16 = Xh;                          // alias: X dead after GEMM1

  cast_x_kernel<<<(TOKENS * KD) / 256, 256, 0, stream>>>(x, Xh, TOKENS * KD);
  pack_wqkv_kernel<<<(NQ * KD) / 256, 256, 0, stream>>>(wqkv_r, wqkv_i, bqkv_r, bqkv_i,
                                                        Wqkv_p, biasq);
  pack_wo_kernel<<<(KD * KD) / 256, 256, 0, stream>>>(wo_r, wo_i, bo_r, bo_i, Wo_p, biaso);

  gemm_tn<true><<<dim3(NQ / 128, TOKENS / 128), 256, 0, stream>>>(
      Xh, Wqkv_p, biasq, (void*)qkQK, QKW, Vt);
  attn_kernel<<<dim3(2048 / 64, 32), 256, 0, stream>>>(qkQK, Vt, attn16);
  gemm_tn<false><<<dim3(KD / 128, TOKENS / 128), 256, 0, stream>>>(
      attn16, Wo_p, biaso, (void*)out, KD, nullptr);
}

// Round 4
// 680.577 us; speedup vs baseline: 1.2914x; 1.2914x over previous
//
#include <hip/hip_runtime.h>

using f16 = _Float16;
typedef f16 f16x8 __attribute__((ext_vector_type(8)));
typedef f16 f16x4 __attribute__((ext_vector_type(4)));
typedef float f32x4 __attribute__((ext_vector_type(4)));

#define TOKENS 4096   // B*N
#define KD 2048       // 2*DIM  (GEMM inner dim, k = 2*dk + ck)
#define NQ 6144       // qkv cols: which*2048 + h*128 + d*2 + c
#define QKW 4128      // PADDED width of Q,K buffer (8256B row stride, non-pow2)
#define VTS 2064      // PADDED token stride of Vt (4128B, non-pow2)

__device__ __forceinline__ void gload_lds16(const void* g, void* l) {
  __builtin_amdgcn_global_load_lds(
      (__attribute__((address_space(1))) void*)(unsigned long long)g,
      (__attribute__((address_space(3))) void*)l, 16, 0, 0);
}

// ---------------- prep kernels ----------------
__global__ __launch_bounds__(256) void cast_x_kernel(const float* __restrict__ x,
                                                     f16* __restrict__ X, int n) {
  int i = blockIdx.x * 256 + threadIdx.x;
  if (i < n) X[i] = (f16)x[i];
}

__global__ __launch_bounds__(256) void pack_wqkv_kernel(const float* __restrict__ wr,
    const float* __restrict__ wi, const float* __restrict__ br, const float* __restrict__ bi,
    f16* __restrict__ Wp, float* __restrict__ biasq) {
  int idx = blockIdx.x * 256 + threadIdx.x;
  if (idx >= NQ * KD) return;
  int j = idx >> 11;
  int k = idx & 2047;
  int which = j >> 11;
  int rem = j & 2047;
  int h = rem >> 7, t = rem & 127, d = t >> 1, c = t & 1;
  int o = which * 1024 + h * 64 + d;
  int dk = k >> 1, ck = k & 1;
  float wrv = wr[o * 1024 + dk], wiv = wi[o * 1024 + dk];
  float v = (c == 0) ? ((ck == 0) ? wrv : -wiv) : ((ck == 0) ? wiv : wrv);
  Wp[idx] = (f16)v;
  if (k == 0) biasq[j] = (c == 0) ? (br[o] - bi[o]) : (br[o] + bi[o]);
}

__global__ __launch_bounds__(256) void pack_wo_kernel(const float* __restrict__ wr,
    const float* __restrict__ wi, const float* __restrict__ br, const float* __restrict__ bi,
    f16* __restrict__ Wp, float* __restrict__ biaso) {
  int idx = blockIdx.x * 256 + threadIdx.x;
  if (idx >= KD * KD) return;
  int j = idx >> 11, k = idx & 2047;
  int jo = j >> 1, c = j & 1;
  int dk = k >> 1, ck = k & 1;
  float wrv = wr[jo * 1024 + dk], wiv = wi[jo * 1024 + dk];
  float v = (c == 0) ? ((ck == 0) ? wrv : -wiv) : ((ck == 0) ? wiv : wrv);
  Wp[idx] = (f16)v;
  if (k == 0) biaso[j] = (c == 0) ? (br[jo] - bi[jo]) : (br[jo] + bi[jo]);
}

// ---------------- GEMM: C[m][n] = sum_k A[m][k]*B[n][k] + bias[n] ----------------
// 128x128 tile, BK=32, 4 waves (2x2). Cols >= 4096 (V of qkv) are written
// TRANSPOSED to vt[b*16+h][d][token] (token stride VTS) for attention's PV.
template<bool HALF_OUT>
__global__ __launch_bounds__(256) void gemm_tn(const f16* __restrict__ A,
    const f16* __restrict__ B, const float* __restrict__ bias,
    void* __restrict__ Cout, int ldc, f16* __restrict__ vt) {
  __shared__ f16 ldsA[128 * 32];
  __shared__ f16 ldsB[128 * 32];
  const int tid = threadIdx.x;
  const int wave = tid >> 6, lane = tid & 63;
  const int lo = lane & 15, hi = lane >> 4;
  const int m0 = blockIdx.y * 128, n0 = blockIdx.x * 128;
  const int wm = wave >> 1, wn = wave & 1;

  const int srow = wave * 32 + (lane >> 2);
  const int scol = (lane & 3) * 8;
  const f16* gA0 = A + (size_t)(m0 + srow) * KD + scol;
  const f16* gA1 = gA0 + (size_t)16 * KD;
  const f16* gB0 = B + (size_t)(n0 + srow) * KD + scol;
  const f16* gB1 = gB0 + (size_t)16 * KD;
  f16* lA0 = &ldsA[wave * 1024];
  f16* lA1 = &ldsA[wave * 1024 + 512];
  f16* lB0 = &ldsB[wave * 1024];
  f16* lB1 = &ldsB[wave * 1024 + 512];

  f32x4 acc[4][4] = {};

  for (int kt = 0; kt < KD; kt += 32) {
    gload_lds16(gA0, lA0);
    gload_lds16(gA1, lA1);
    gload_lds16(gB0, lB0);
    gload_lds16(gB1, lB1);
    gA0 += 32; gA1 += 32; gB0 += 32; gB1 += 32;
    __syncthreads();
    f16x8 af[4], bf[4];
    #pragma unroll
    for (int mi = 0; mi < 4; ++mi)
      af[mi] = *(const f16x8*)&ldsA[(wm * 64 + mi * 16 + lo) * 32 + hi * 8];
    #pragma unroll
    for (int ni = 0; ni < 4; ++ni)
      bf[ni] = *(const f16x8*)&ldsB[(wn * 64 + ni * 16 + lo) * 32 + hi * 8];
    #pragma unroll
    for (int mi = 0; mi < 4; ++mi)
      #pragma unroll
      for (int ni = 0; ni < 4; ++ni)
        acc[mi][ni] = __builtin_amdgcn_mfma_f32_16x16x32_f16(af[mi], bf[ni], acc[mi][ni], 0, 0, 0);
    __syncthreads();
  }

  #pragma unroll
  for (int mi = 0; mi < 4; ++mi) {
    #pragma unroll
    for (int ni = 0; ni < 4; ++ni) {
      const int colbase = n0 + wn * 64 + ni * 16;
      const int col = colbase + lo;
      const float bv = bias[col];
      const int rowb = m0 + wm * 64 + mi * 16 + hi * 4;  // D: row = 4*hi + r, col = lo
      if (vt != nullptr && colbase >= 4096) {
        // V block -> transposed store: 4 consecutive tokens at fixed d
        const int dcol = col - 4096;
        const int hh = dcol >> 7, dd = dcol & 127;
        const int bb = rowb >> 11, tok = rowb & 2047;
        f16x4 pk;
        #pragma unroll
        for (int r = 0; r < 4; ++r) pk[r] = (f16)(acc[mi][ni][r] + bv);
        *(f16x4*)(vt + ((size_t)(bb * 16 + hh) * 128 + dd) * VTS + tok) = pk;
      } else {
        #pragma unroll
        for (int r = 0; r < 4; ++r) {
          const float v = acc[mi][ni][r] + bv;
          if (HALF_OUT) ((f16*)Cout)[(size_t)(rowb + r) * ldc + col] = (f16)v;
          else          ((float*)Cout)[(size_t)(rowb + r) * ldc + col] = v;
        }
      }
    }
  }
}

// ---------------- flash attention, per (b,h), wave = 16 q-rows, KV tile 32 ----
// Swapped QK^T: mfma(K,Q) => lane holds S[q=lo][kv = t + 16*tt + 4*hi + r].
// P is directly the A-fragment of mfma_f32_16x16x16f16 for PV; V read from Vt
// (d-major, padded stride) as contiguous f16x4 over tokens.
__global__ __launch_bounds__(256) void attn_kernel(const f16* __restrict__ qk,
                                                   const f16* __restrict__ vt,
                                                   f16* __restrict__ outp) {
  const int wave = threadIdx.x >> 6, lane = threadIdx.x & 63;
  const int lo = lane & 15, hi = lane >> 4;

  // XCD-chunked swizzle (T1): dispatch slot -> work id such that each XCD
  // (slot % 8) owns 128 consecutive work ids = 4 full (b,h) groups (4MB = L2).
  const int flat = blockIdx.x + gridDim.x * blockIdx.y;   // 0..1023
  const int nf = (flat & 7) * 128 + (flat >> 3);
  const int by = nf >> 5, bx = nf & 31;
  const int b = by >> 4, h = by & 15;
  const int q0 = bx * 64 + wave * 16;

  const f16* Qb = qk + (size_t)b * 2048 * QKW + h * 128;
  const f16* Kb = Qb + 2048;
  const f16* Vtb = vt + (size_t)(b * 16 + h) * 128 * VTS;

  f16x8 qf[4];
  #pragma unroll
  for (int c = 0; c < 4; ++c) {
    qf[c] = *(const f16x8*)(Qb + (size_t)(q0 + lo) * QKW + c * 32 + hi * 8);
    qf[c] *= (f16)0.125f;   // fold attn scale (exact pow2) into Q
  }

  f32x4 o[8];
  #pragma unroll
  for (int dc = 0; dc < 8; ++dc) o[dc] = (f32x4){0.f, 0.f, 0.f, 0.f};
  float m_run = -INFINITY, l_run = 0.f;

  for (int t = 0; t < 2048; t += 32) {
    f32x4 s0 = {0.f, 0.f, 0.f, 0.f}, s1 = {0.f, 0.f, 0.f, 0.f};
    #pragma unroll
    for (int c = 0; c < 4; ++c) {
      f16x8 kf = *(const f16x8*)(Kb + (size_t)(t + lo) * QKW + c * 32 + hi * 8);
      s0 = __builtin_amdgcn_mfma_f32_16x16x32_f16(kf, qf[c], s0, 0, 0, 0);
    }
    #pragma unroll
    for (int c = 0; c < 4; ++c) {
      f16x8 kf = *(const f16x8*)(Kb + (size_t)(t + 16 + lo) * QKW + c * 32 + hi * 8);
      s1 = __builtin_amdgcn_mfma_f32_16x16x32_f16(kf, qf[c], s1, 0, 0, 0);
    }

    // per-q max over this 32-kv tile (q = lo; kv spread over regs + hi groups)
    float pm = fmaxf(fmaxf(fmaxf(s0[0], s0[1]), fmaxf(s0[2], s0[3])),
                     fmaxf(fmaxf(s1[0], s1[1]), fmaxf(s1[2], s1[3])));
    pm = fmaxf(pm, __shfl_xor(pm, 16));
    pm = fmaxf(pm, __shfl_xor(pm, 32));

    // defer-max (T13): only rescale when some row's max grew by > 8
    if (!__all(pm - m_run <= 8.f)) {
      const float corr = __expf(m_run - pm);   // exp(-inf)=0 on first tile
      m_run = pm;
      float co[4];
      #pragma unroll
      for (int r = 0; r < 4; ++r) co[r] = __shfl(corr, hi * 4 + r);
      #pragma unroll
      for (int dc = 0; dc < 8; ++dc)
        #pragma unroll
        for (int r = 0; r < 4; ++r) o[dc][r] *= co[r];
      l_run *= corr;
    }

    float psum = 0.f;
    f16x4 pf0, pf1;
    #pragma unroll
    for (int r = 0; r < 4; ++r) {
      float p0 = __expf(s0[r] - m_run);
      float p1 = __expf(s1[r] - m_run);
      psum += p0 + p1;
      pf0[r] = (f16)p0;
      pf1[r] = (f16)p1;
    }
    psum += __shfl_xor(psum, 16);
    psum += __shfl_xor(psum, 32);
    l_run += psum;

    #pragma unroll
    for (int dc = 0; dc < 8; ++dc) {
      const f16* vp = Vtb + (size_t)(dc * 16 + lo) * VTS + t + hi * 4;
      f16x4 vf0 = *(const f16x4*)vp;
      f16x4 vf1 = *(const f16x4*)(vp + 16);
      o[dc] = __builtin_amdgcn_mfma_f32_16x16x16f16(pf0, vf0, o[dc], 0, 0, 0);
      o[dc] = __builtin_amdgcn_mfma_f32_16x16x16f16(pf1, vf1, o[dc], 0, 0, 0);
    }
  }

  float inv[4];
  #pragma unroll
  for (int r = 0; r < 4; ++r) inv[r] = 1.f / __shfl(l_run, hi * 4 + r);

  const int tok0 = b * 2048 + q0;
  #pragma unroll
  for (int dc = 0; dc < 8; ++dc)
    #pragma unroll
    for (int r = 0; r < 4; ++r)
      outp[(size_t)(tok0 + hi * 4 + r) * KD + h * 128 + dc * 16 + lo] =
          (f16)(o[dc][r] * inv[r]);
}

// ---------------- launch ----------------
extern "C" void kernel_launch(void* const* d_in, const int* in_sizes, int n_in,
                              void* d_out, int out_size, void* d_ws, size_t ws_size,
                              hipStream_t stream) {
  const float* x      = (const float*)d_in[0];
  const float* wqkv_r = (const float*)d_in[1];
  const float* wqkv_i = (const float*)d_in[2];
  const float* bqkv_r = (const float*)d_in[3];
  const float* bqkv_i = (const float*)d_in[4];
  const float* wo_r   = (const float*)d_in[5];
  const float* wo_i   = (const float*)d_in[6];
  const float* bo_r   = (const float*)d_in[7];
  const float* bo_i   = (const float*)d_in[8];
  float* out = (float*)d_out;
  char* ws = (char*)d_ws;

  // workspace layout (~96.4 MB)
  f16*   Wqkv_p = (f16*)(ws + 0);              // 6144*2048*2    = 25165824
  f16*   Wo_p   = (f16*)(ws + 25165824);       // 2048*2048*2    =  8388608
  float* biasq  = (float*)(ws + 33554432);     // 6144*4
  float* biaso  = (float*)(ws + 33579008);     // 2048*4
  f16*   qkQK   = (f16*)(ws + 33587200);       // 4096*4128*2    = 33816576 (Q,K padded)
  f16*   Vt     = (f16*)(ws + 67403776);       // 32*128*2064*2  = 16908288 (V^T padded)
  f16*   Xh     = (f16*)(ws + 84312064);       // 4096*2048*2    = 16777216
  f16*   attn16 = Xh;                          // alias: X dead after GEMM1

  cast_x_kernel<<<(TOKENS * KD) / 256, 256, 0, stream>>>(x, Xh, TOKENS * KD);
  pack_wqkv_kernel<<<(NQ * KD) / 256, 256, 0, stream>>>(wqkv_r, wqkv_i, bqkv_r, bqkv_i,
                                                        Wqkv_p, biasq);
  pack_wo_kernel<<<(KD * KD) / 256, 256, 0, stream>>>(wo_r, wo_i, bo_r, bo_i, Wo_p, biaso);

  gemm_tn<true><<<dim3(NQ / 128, TOKENS / 128), 256, 0, stream>>>(
      Xh, Wqkv_p, biasq, (void*)qkQK, QKW, Vt);
  attn_kernel<<<dim3(2048 / 64, 32), 256, 0, stream>>>(qkQK, Vt, attn16);
  gemm_tn<false><<<dim3(KD / 128, TOKENS / 128), 256, 0, stream>>>(
      attn16, Wo_p, biaso, (void*)out, KD, nullptr);
}

// Round 5
// 333.423 us; speedup vs baseline: 2.6359x; 2.0412x over previous
//
#include <hip/hip_runtime.h>

using f16 = _Float16;
typedef f16 f16x8 __attribute__((ext_vector_type(8)));
typedef f16 f16x4 __attribute__((ext_vector_type(4)));
typedef float f32x4 __attribute__((ext_vector_type(4)));

#define TOKENS 4096   // B*N
#define KD 2048       // 2*DIM  (GEMM inner dim, k = 2*dk + ck)
#define NQ 6144       // qkv cols: which*2048 + h*128 + d*2 + c
#define QKW 4128      // PADDED width of Q,K buffer (8256B row stride, non-pow2)
#define VTS 2064      // PADDED token stride of Vt (4128B, non-pow2)

__device__ __forceinline__ void gload_lds16(const void* g, void* l) {
  __builtin_amdgcn_global_load_lds(
      (__attribute__((address_space(1))) void*)(unsigned long long)g,
      (__attribute__((address_space(3))) void*)l, 16, 0, 0);
}

// ---------------- prep kernels ----------------
__global__ __launch_bounds__(256) void cast_x_kernel(const float* __restrict__ x,
                                                     f16* __restrict__ X, int n) {
  int i = blockIdx.x * 256 + threadIdx.x;
  if (i < n) X[i] = (f16)x[i];
}

__global__ __launch_bounds__(256) void pack_wqkv_kernel(const float* __restrict__ wr,
    const float* __restrict__ wi, const float* __restrict__ br, const float* __restrict__ bi,
    f16* __restrict__ Wp, float* __restrict__ biasq) {
  int idx = blockIdx.x * 256 + threadIdx.x;
  if (idx >= NQ * KD) return;
  int j = idx >> 11;
  int k = idx & 2047;
  int which = j >> 11;
  int rem = j & 2047;
  int h = rem >> 7, t = rem & 127, d = t >> 1, c = t & 1;
  int o = which * 1024 + h * 64 + d;
  int dk = k >> 1, ck = k & 1;
  float wrv = wr[o * 1024 + dk], wiv = wi[o * 1024 + dk];
  float v = (c == 0) ? ((ck == 0) ? wrv : -wiv) : ((ck == 0) ? wiv : wrv);
  Wp[idx] = (f16)v;
  if (k == 0) biasq[j] = (c == 0) ? (br[o] - bi[o]) : (br[o] + bi[o]);
}

__global__ __launch_bounds__(256) void pack_wo_kernel(const float* __restrict__ wr,
    const float* __restrict__ wi, const float* __restrict__ br, const float* __restrict__ bi,
    f16* __restrict__ Wp, float* __restrict__ biaso) {
  int idx = blockIdx.x * 256 + threadIdx.x;
  if (idx >= KD * KD) return;
  int j = idx >> 11, k = idx & 2047;
  int jo = j >> 1, c = j & 1;
  int dk = k >> 1, ck = k & 1;
  float wrv = wr[jo * 1024 + dk], wiv = wi[jo * 1024 + dk];
  float v = (c == 0) ? ((ck == 0) ? wrv : -wiv) : ((ck == 0) ? wiv : wrv);
  Wp[idx] = (f16)v;
  if (k == 0) biaso[j] = (c == 0) ? (br[jo] - bi[jo]) : (br[jo] + bi[jo]);
}

// ---------------- GEMM: C[m][n] = sum_k A[m][k]*B[n][k] + bias[n] ----------------
// 128x128 tile, BK=32, 4 waves (2x2). Cols >= 4096 (V of qkv) are written
// TRANSPOSED to vt[b*16+h][d][token] (token stride VTS) for attention's PV.
template<bool HALF_OUT>
__global__ __launch_bounds__(256) void gemm_tn(const f16* __restrict__ A,
    const f16* __restrict__ B, const float* __restrict__ bias,
    void* __restrict__ Cout, int ldc, f16* __restrict__ vt) {
  __shared__ f16 ldsA[128 * 32];
  __shared__ f16 ldsB[128 * 32];
  const int tid = threadIdx.x;
  const int wave = tid >> 6, lane = tid & 63;
  const int lo = lane & 15, hi = lane >> 4;
  const int m0 = blockIdx.y * 128, n0 = blockIdx.x * 128;
  const int wm = wave >> 1, wn = wave & 1;

  const int srow = wave * 32 + (lane >> 2);
  const int scol = (lane & 3) * 8;
  const f16* gA0 = A + (size_t)(m0 + srow) * KD + scol;
  const f16* gA1 = gA0 + (size_t)16 * KD;
  const f16* gB0 = B + (size_t)(n0 + srow) * KD + scol;
  const f16* gB1 = gB0 + (size_t)16 * KD;
  f16* lA0 = &ldsA[wave * 1024];
  f16* lA1 = &ldsA[wave * 1024 + 512];
  f16* lB0 = &ldsB[wave * 1024];
  f16* lB1 = &ldsB[wave * 1024 + 512];

  f32x4 acc[4][4] = {};

  for (int kt = 0; kt < KD; kt += 32) {
    gload_lds16(gA0, lA0);
    gload_lds16(gA1, lA1);
    gload_lds16(gB0, lB0);
    gload_lds16(gB1, lB1);
    gA0 += 32; gA1 += 32; gB0 += 32; gB1 += 32;
    __syncthreads();
    f16x8 af[4], bf[4];
    #pragma unroll
    for (int mi = 0; mi < 4; ++mi)
      af[mi] = *(const f16x8*)&ldsA[(wm * 64 + mi * 16 + lo) * 32 + hi * 8];
    #pragma unroll
    for (int ni = 0; ni < 4; ++ni)
      bf[ni] = *(const f16x8*)&ldsB[(wn * 64 + ni * 16 + lo) * 32 + hi * 8];
    #pragma unroll
    for (int mi = 0; mi < 4; ++mi)
      #pragma unroll
      for (int ni = 0; ni < 4; ++ni)
        acc[mi][ni] = __builtin_amdgcn_mfma_f32_16x16x32_f16(af[mi], bf[ni], acc[mi][ni], 0, 0, 0);
    __syncthreads();
  }

  #pragma unroll
  for (int mi = 0; mi < 4; ++mi) {
    #pragma unroll
    for (int ni = 0; ni < 4; ++ni) {
      const int colbase = n0 + wn * 64 + ni * 16;
      const int col = colbase + lo;
      const float bv = bias[col];
      const int rowb = m0 + wm * 64 + mi * 16 + hi * 4;  // D: row = 4*hi + r, col = lo
      if (vt != nullptr && colbase >= 4096) {
        // V block -> transposed store: 4 consecutive tokens at fixed d
        const int dcol = col - 4096;
        const int hh = dcol >> 7, dd = dcol & 127;
        const int bb = rowb >> 11, tok = rowb & 2047;
        f16x4 pk;
        #pragma unroll
        for (int r = 0; r < 4; ++r) pk[r] = (f16)(acc[mi][ni][r] + bv);
        *(f16x4*)(vt + ((size_t)(bb * 16 + hh) * 128 + dd) * VTS + tok) = pk;
      } else {
        #pragma unroll
        for (int r = 0; r < 4; ++r) {
          const float v = acc[mi][ni][r] + bv;
          if (HALF_OUT) ((f16*)Cout)[(size_t)(rowb + r) * ldc + col] = (f16)v;
          else          ((float*)Cout)[(size_t)(rowb + r) * ldc + col] = v;
        }
      }
    }
  }
}

// ---------------- flash attention v3: LDS-staged K/V, 128 q-rows per block ----
// Block = 4 waves; wave owns 32 q-rows (two 16-row MFMA blocks qb=0,1).
// Per 32-token step: stage K[32][128] + Vt[128][32] into LDS (double-buffered,
// global_load_lds w16, XOR-swizzled 16B chunks), then swapped QK^T + online
// softmax + PV. K frags + V frags shared across both q-blocks.
__global__ __launch_bounds__(256) void attn_kernel(const f16* __restrict__ qk,
                                                   const f16* __restrict__ vt,
                                                   f16* __restrict__ outp) {
  __shared__ __align__(16) f16 lds[2][8192];  // per buf: K at [0..4096), V at [4096..8192)
  const int tid = threadIdx.x;
  const int wave = tid >> 6, lane = tid & 63;
  const int lo = lane & 15, hi = lane >> 4;

  // XCD-chunked swizzle: 512 blocks, each XCD owns 64 consecutive work ids
  const int flat = blockIdx.x;
  const int nf = (flat & 7) * 64 + (flat >> 3);
  const int by = nf >> 4, bx = nf & 15;   // by: (b,h); bx: q-tile of 128 rows
  const int b = by >> 4, h = by & 15;
  const int q0 = bx * 128 + wave * 32;

  const f16* Qb = qk + (size_t)b * 2048 * QKW + h * 128;
  const f16* Kb = Qb + 2048;
  const f16* Vtb = vt + (size_t)(b * 16 + h) * 128 * VTS;

  // Q fragments for both 16-row blocks; fold 0.125 scale into Q
  f16x8 qf[2][4];
  #pragma unroll
  for (int qb = 0; qb < 2; ++qb)
    #pragma unroll
    for (int c = 0; c < 4; ++c) {
      qf[qb][c] = *(const f16x8*)(Qb + (size_t)(q0 + qb * 16 + lo) * QKW + c * 32 + hi * 8);
      qf[qb][c] *= (f16)0.125f;
    }

  f32x4 o[2][8];
  #pragma unroll
  for (int qb = 0; qb < 2; ++qb)
    #pragma unroll
    for (int dc = 0; dc < 8; ++dc) o[qb][dc] = (f32x4){0.f, 0.f, 0.f, 0.f};
  float m_run[2] = {-INFINITY, -INFINITY};
  float l_run[2] = {0.f, 0.f};

  const int cl0 = wave * 64 + lane;

  // stage tile t..t+32 into buffer buf. LDS dest linear (wave-uniform base +
  // lane*16); inverse XOR-swizzle applied to the per-lane GLOBAL source.
  auto STAGE = [&](int buf, int t) {
    #pragma unroll
    for (int rnd = 0; rnd < 2; ++rnd) {
      const int cl = rnd * 256 + cl0;
      const int row = cl >> 4;                      // 0..31 (token in tile)
      const int gch = (cl & 15) ^ (row & 7);        // 16B chunk in K row
      gload_lds16(Kb + (size_t)(t + row) * QKW + gch * 8,
                  &lds[buf][(size_t)(rnd * 256 + wave * 64) * 8]);
    }
    #pragma unroll
    for (int rnd = 0; rnd < 2; ++rnd) {
      const int cl = rnd * 256 + cl0;
      const int d = cl >> 2;                        // 0..127
      const int gch = (cl & 3) ^ ((d >> 1) & 3);    // 16B chunk in V row (8 tok)
      gload_lds16(Vtb + (size_t)d * VTS + t + gch * 8,
                  &lds[buf][4096 + (size_t)(rnd * 256 + wave * 64) * 8]);
    }
  };

  STAGE(0, 0);
  int cur = 0;

  for (int it = 0; it < 64; ++it) {
    __syncthreads();                 // drains vmcnt -> lds[cur] ready; prev reads done
    if (it + 1 < 64) STAGE(cur ^ 1, (it + 1) * 32);

    const f16* ldsK = lds[cur];
    const f16* ldsV = lds[cur] + 4096;

    // K fragments (shared by both q-blocks): row = tt*16+lo, chunk (c*4+hi)^(row&7)
    f16x8 kf[2][4];
    #pragma unroll
    for (int tt = 0; tt < 2; ++tt)
      #pragma unroll
      for (int c = 0; c < 4; ++c) {
        const int row = tt * 16 + lo;
        const int ch = (c * 4 + hi) ^ (row & 7);
        kf[tt][c] = *(const f16x8*)&ldsK[row * 128 + ch * 8];
      }

    f16x4 pf[2][2];
    #pragma unroll
    for (int qb = 0; qb < 2; ++qb) {
      f32x4 s0 = {0.f, 0.f, 0.f, 0.f}, s1 = {0.f, 0.f, 0.f, 0.f};
      #pragma unroll
      for (int c = 0; c < 4; ++c) {
        s0 = __builtin_amdgcn_mfma_f32_16x16x32_f16(kf[0][c], qf[qb][c], s0, 0, 0, 0);
        s1 = __builtin_amdgcn_mfma_f32_16x16x32_f16(kf[1][c], qf[qb][c], s1, 0, 0, 0);
      }

      float pm = fmaxf(fmaxf(fmaxf(s0[0], s0[1]), fmaxf(s0[2], s0[3])),
                       fmaxf(fmaxf(s1[0], s1[1]), fmaxf(s1[2], s1[3])));
      pm = fmaxf(pm, __shfl_xor(pm, 16));
      pm = fmaxf(pm, __shfl_xor(pm, 32));

      if (!__all(pm - m_run[qb] <= 8.f)) {   // defer-max (T13)
        const float corr = __expf(m_run[qb] - pm);
        m_run[qb] = pm;
        float co[4];
        #pragma unroll
        for (int r = 0; r < 4; ++r) co[r] = __shfl(corr, hi * 4 + r);
        #pragma unroll
        for (int dc = 0; dc < 8; ++dc)
          #pragma unroll
          for (int r = 0; r < 4; ++r) o[qb][dc][r] *= co[r];
        l_run[qb] *= corr;
      }

      float psum = 0.f;
      #pragma unroll
      for (int r = 0; r < 4; ++r) {
        const float p0 = __expf(s0[r] - m_run[qb]);
        const float p1 = __expf(s1[r] - m_run[qb]);
        psum += p0 + p1;
        pf[qb][0][r] = (f16)p0;
        pf[qb][1][r] = (f16)p1;
      }
      psum += __shfl_xor(psum, 16);
      psum += __shfl_xor(psum, 32);
      l_run[qb] += psum;
    }

    // PV: V fragments shared by both q-blocks. d = dc*16+lo; tokens tt*16+hi*4..+3
    #pragma unroll
    for (int dc = 0; dc < 8; ++dc) {
      const int d = dc * 16 + lo;
      f16x4 vf[2];
      #pragma unroll
      for (int tt = 0; tt < 2; ++tt) {
        const int ch = (tt * 2 + (hi >> 1)) ^ ((d >> 1) & 3);
        vf[tt] = *(const f16x4*)&ldsV[d * 32 + ch * 8 + (hi & 1) * 4];
      }
      o[0][dc] = __builtin_amdgcn_mfma_f32_16x16x16f16(pf[0][0], vf[0], o[0][dc], 0, 0, 0);
      o[0][dc] = __builtin_amdgcn_mfma_f32_16x16x16f16(pf[0][1], vf[1], o[0][dc], 0, 0, 0);
      o[1][dc] = __builtin_amdgcn_mfma_f32_16x16x16f16(pf[1][0], vf[0], o[1][dc], 0, 0, 0);
      o[1][dc] = __builtin_amdgcn_mfma_f32_16x16x16f16(pf[1][1], vf[1], o[1][dc], 0, 0, 0);
    }

    cur ^= 1;
  }

  #pragma unroll
  for (int qb = 0; qb < 2; ++qb) {
    float inv[4];
    #pragma unroll
    for (int r = 0; r < 4; ++r) inv[r] = 1.f / __shfl(l_run[qb], hi * 4 + r);
    const int tok0 = b * 2048 + q0 + qb * 16;
    #pragma unroll
    for (int dc = 0; dc < 8; ++dc)
      #pragma unroll
      for (int r = 0; r < 4; ++r)
        outp[(size_t)(tok0 + hi * 4 + r) * KD + h * 128 + dc * 16 + lo] =
            (f16)(o[qb][dc][r] * inv[r]);
  }
}

// ---------------- launch ----------------
extern "C" void kernel_launch(void* const* d_in, const int* in_sizes, int n_in,
                              void* d_out, int out_size, void* d_ws, size_t ws_size,
                              hipStream_t stream) {
  const float* x      = (const float*)d_in[0];
  const float* wqkv_r = (const float*)d_in[1];
  const float* wqkv_i = (const float*)d_in[2];
  const float* bqkv_r = (const float*)d_in[3];
  const float* bqkv_i = (const float*)d_in[4];
  const float* wo_r   = (const float*)d_in[5];
  const float* wo_i   = (const float*)d_in[6];
  const float* bo_r   = (const float*)d_in[7];
  const float* bo_i   = (const float*)d_in[8];
  float* out = (float*)d_out;
  char* ws = (char*)d_ws;

  // workspace layout (~96.4 MB)
  f16*   Wqkv_p = (f16*)(ws + 0);              // 6144*2048*2    = 25165824
  f16*   Wo_p   = (f16*)(ws + 25165824);       // 2048*2048*2    =  8388608
  float* biasq  = (float*)(ws + 33554432);     // 6144*4
  float* biaso  = (float*)(ws + 33579008);     // 2048*4
  f16*   qkQK   = (f16*)(ws + 33587200);       // 4096*4128*2    = 33816576 (Q,K padded)
  f16*   Vt     = (f16*)(ws + 67403776);       // 32*128*2064*2  = 16908288 (V^T padded)
  f16*   Xh     = (f16*)(ws + 84312064);       // 4096*2048*2    = 16777216
  f16*   attn16 = Xh;                          // alias: X dead after GEMM1

  cast_x_kernel<<<(TOKENS * KD) / 256, 256, 0, stream>>>(x, Xh, TOKENS * KD);
  pack_wqkv_kernel<<<(NQ * KD) / 256, 256, 0, stream>>>(wqkv_r, wqkv_i, bqkv_r, bqkv_i,
                                                        Wqkv_p, biasq);
  pack_wo_kernel<<<(KD * KD) / 256, 256, 0, stream>>>(wo_r, wo_i, bo_r, bo_i, Wo_p, biaso);

  gemm_tn<true><<<dim3(NQ / 128, TOKENS / 128), 256, 0, stream>>>(
      Xh, Wqkv_p, biasq, (void*)qkQK, QKW, Vt);
  attn_kernel<<<512, 256, 0, stream>>>(qkQK, Vt, attn16);
  gemm_tn<false><<<dim3(KD / 128, TOKENS / 128), 256, 0, stream>>>(
      attn16, Wo_p, biaso, (void*)out, KD, nullptr);
}